// Round 11
// baseline (648.064 us; speedup 1.0000x reference)
//
#include <hip/hip_runtime.h>

#define N_NODES 25600
#define N_EDGES 409600
#define EPSV 1e-5f

__device__ __forceinline__ unsigned short f2bf(float f) {
    unsigned int x = __float_as_uint(f);
    x += 0x7fffu + ((x >> 16) & 1u);
    return (unsigned short)(x >> 16);
}

using frag_ab = __attribute__((ext_vector_type(8))) short;  // 8 bf16 = 4 VGPRs
using frag_cd = __attribute__((ext_vector_type(4))) float;

#define WST 104   // gate/final LDS row stride (bf16): 208 B, 16B-aligned, non-pow-2
#define TWST 72   // transform weight LDS stride (bf16)
#define THST 200  // transform h/y1 LDS stride (bf16)

// ---------------- fused transform: x[n,0:96] = W2g·prelu(W1g·h[n]+b1)+b2, grouped, MFMA ----------------
__global__ __launch_bounds__(256) void transform_mfma(
    const float* __restrict__ h,
    const float* __restrict__ tpw1, const float* __restrict__ tpb1, const float* __restrict__ tpa,
    const float* __restrict__ tpw2, const float* __restrict__ tpb2,
    const float* __restrict__ tmw1, const float* __restrict__ tmb1, const float* __restrict__ tma,
    const float* __restrict__ tmw2, const float* __restrict__ tmb2,
    float* __restrict__ xout)
{
    __shared__ alignas(16) unsigned short W1s[192 * TWST]; // [o][i] bf16
    __shared__ alignas(16) unsigned short W2s[96 * TWST];  // [o][i] bf16
    __shared__ alignas(16) unsigned short hs[64 * THST];   // [m][c] bf16; y1 overwrites in place
    __shared__ float b1s[192];
    __shared__ float b2s[96];

    const int tid = threadIdx.x;
    const int s = blockIdx.y;
    const float* w1 = s ? tmw1 : tpw1;
    const float* b1 = s ? tmb1 : tpb1;
    const float* w2 = s ? tmw2 : tpw2;
    const float* b2 = s ? tmb2 : tpb2;
    const float alpha = (s ? tma : tpa)[0];

    #pragma unroll
    for (int r = 0; r < 12; r++) {
        int idx4 = r * 256 + tid;                    // over 192*16
        int o = idx4 >> 4, i4 = (idx4 & 15) * 4;
        const float4 a = *(const float4*)&w1[o * 64 + i4];
        unsigned int lo = (unsigned int)f2bf(a.x) | ((unsigned int)f2bf(a.y) << 16);
        unsigned int hi = (unsigned int)f2bf(a.z) | ((unsigned int)f2bf(a.w) << 16);
        *(uint2*)&W1s[o * TWST + i4] = make_uint2(lo, hi);
    }
    #pragma unroll
    for (int r = 0; r < 6; r++) {
        int idx4 = r * 256 + tid;                    // over 96*16
        int o = idx4 >> 4, i4 = (idx4 & 15) * 4;
        const float4 a = *(const float4*)&w2[o * 64 + i4];
        unsigned int lo = (unsigned int)f2bf(a.x) | ((unsigned int)f2bf(a.y) << 16);
        unsigned int hi = (unsigned int)f2bf(a.z) | ((unsigned int)f2bf(a.w) << 16);
        *(uint2*)&W2s[o * TWST + i4] = make_uint2(lo, hi);
    }
    if (tid < 192) b1s[tid] = b1[tid];
    if (tid < 96) b2s[tid] = b2[tid];
    __syncthreads();

    const int lane = tid & 63;
    const int wv = tid >> 6;
    const int quad = lane >> 4;
    const int lcol = lane & 15;
    const int m0 = wv * 16;
    const int j0 = blockIdx.x * 64;

    #pragma unroll
    for (int r = 0; r < 12; r++) {
        int idx = r * 256 + tid;                     // over 64*48 float4s
        int m = idx / 48, q = idx - m * 48;
        const float4 a = *(const float4*)&h[(2 * (j0 + m) + s) * 192 + q * 4];
        unsigned int lo = (unsigned int)f2bf(a.x) | ((unsigned int)f2bf(a.y) << 16);
        unsigned int hi = (unsigned int)f2bf(a.z) | ((unsigned int)f2bf(a.w) << 16);
        *(uint2*)&hs[m * THST + q * 4] = make_uint2(lo, hi);
    }
    __syncthreads();

    const int arow = (m0 + lcol) * THST;
    #pragma unroll
    for (int g = 0; g < 3; g++) {
        frag_cd acc[4];
        #pragma unroll
        for (int nt = 0; nt < 4; nt++) acc[nt] = (frag_cd){0.f, 0.f, 0.f, 0.f};
        #pragma unroll
        for (int kt = 0; kt < 2; kt++) {
            const int k0 = kt * 32 + quad * 8;
            frag_ab af = *(const frag_ab*)&hs[arow + g * 64 + k0];
            #pragma unroll
            for (int nt = 0; nt < 4; nt++) {
                frag_ab bf = *(const frag_ab*)&W1s[(g * 64 + nt * 16 + lcol) * TWST + k0];
                acc[nt] = __builtin_amdgcn_mfma_f32_16x16x32_bf16(af, bf, acc[nt], 0, 0, 0);
            }
        }
        #pragma unroll
        for (int nt = 0; nt < 4; nt++) {
            const int o = g * 64 + nt * 16 + lcol;
            const float bv = b1s[o];
            #pragma unroll
            for (int reg = 0; reg < 4; reg++) {
                float u = acc[nt][reg] + bv;
                u = u >= 0.f ? u : alpha * u;
                hs[(m0 + quad * 4 + reg) * THST + o] = f2bf(u);
            }
        }
    }
    #pragma unroll
    for (int g2 = 0; g2 < 3; g2++) {
        frag_cd acc[2];
        acc[0] = (frag_cd){0.f, 0.f, 0.f, 0.f};
        acc[1] = (frag_cd){0.f, 0.f, 0.f, 0.f};
        #pragma unroll
        for (int kt = 0; kt < 2; kt++) {
            const int k0 = kt * 32 + quad * 8;
            frag_ab af = *(const frag_ab*)&hs[arow + g2 * 64 + k0];
            #pragma unroll
            for (int nt = 0; nt < 2; nt++) {
                frag_ab bf = *(const frag_ab*)&W2s[(g2 * 32 + nt * 16 + lcol) * TWST + k0];
                acc[nt] = __builtin_amdgcn_mfma_f32_16x16x32_bf16(af, bf, acc[nt], 0, 0, 0);
            }
        }
        #pragma unroll
        for (int nt = 0; nt < 2; nt++) {
            const int o2 = g2 * 32 + nt * 16 + lcol;
            const float bv = b2s[o2];
            #pragma unroll
            for (int reg = 0; reg < 4; reg++) {
                const int node = 2 * (j0 + m0 + quad * 4 + reg) + s;
                xout[node * 96 + o2] = acc[nt][reg] + bv;
            }
        }
    }
}

// ---------------- gate (MFMA): e = tanh(prelu((x[dst]*x[src]) @ W1 + b1) @ W2 + b2) ----------------
// WAVE-PRIVATE tiles: each wave owns a 16-edge chunk with its own LDS h2 slice.
// No __syncthreads in the hot loop — within-wave ds_write->ds_read ordering is
// enforced by compiler lgkmcnt waits; waves slip freely to hide gather latency.
template<bool DUAL>
__global__ __launch_bounds__(256) void gate_kernel(
    const float* __restrict__ xf,
    const int* __restrict__ src, const int* __restrict__ dst,
    const float* __restrict__ gW1, const float* __restrict__ gb1,
    const float* __restrict__ ga,  const float* __restrict__ gW2,
    const float* __restrict__ gb2, int layerA, int layerB,
    float* __restrict__ outA, float* __restrict__ outB)
{
    __shared__ alignas(16) unsigned short W1t[(DUAL ? 2 : 1) * 96 * WST]; // [n][k] bf16
    __shared__ alignas(16) unsigned short h2s[4][16 * WST];               // per-wave slice
    __shared__ float W2s[(DUAL ? 2 : 1) * 96];
    __shared__ float b1s[(DUAL ? 2 : 1) * 96];

    const int tid = threadIdx.x;
    {
        const float* W1p = gW1 + layerA * 9216;
        for (int idx = tid; idx < 9216; idx += 256) {
            int k = idx / 96, n = idx - k * 96;
            W1t[n * WST + k] = f2bf(W1p[idx]);
        }
        if (DUAL) {
            const float* W1q = gW1 + layerB * 9216;
            for (int idx = tid; idx < 9216; idx += 256) {
                int k = idx / 96, n = idx - k * 96;
                W1t[96 * WST + n * WST + k] = f2bf(W1q[idx]);
            }
        }
    }
    if (tid < 96) {
        W2s[tid] = gW2[layerA * 96 + tid];
        b1s[tid] = gb1[layerA * 96 + tid];
        if (DUAL) {
            W2s[96 + tid] = gW2[layerB * 96 + tid];
            b1s[96 + tid] = gb1[layerB * 96 + tid];
        }
    }
    const float alphaA = ga[layerA];
    const float b2A = gb2[layerA];
    const float alphaB = DUAL ? ga[layerB] : 0.f;
    const float b2B = DUAL ? gb2[layerB] : 0.f;
    __syncthreads();                                  // one-time weight staging only

    const int lane = tid & 63;
    const int wv   = tid >> 6;
    const int quad = lane >> 4;
    const int lcol = lane & 15;
    unsigned short* h2w = &h2s[wv][0];

    for (int chunk = blockIdx.x * 4 + wv; chunk < N_EDGES / 16; chunk += gridDim.x * 4) {
        const int e16 = chunk * 16 + lcol;            // lanes 0..15 hold the 16 edge ids
        const int si = src[e16] * 96;
        const int di = dst[e16] * 96;
        // phase 1: wave-private gather 16 edges x 96 dims -> bf16 product -> own LDS slice.
        // lanes 0..23 cover one row contiguously (384 B) -> same coalescing as block version.
        #pragma unroll
        for (int i = 0; i < 6; i++) {
            int idx = i * 64 + lane;                  // 0..383 over 16 rows x 24 float4s
            int eL = idx / 24, q = idx - eL * 24;
            int sA = __shfl(si, eL, 64);
            int dA = __shfl(di, eL, 64);
            const float4 a = *(const float4*)&xf[sA + q * 4];
            const float4 b = *(const float4*)&xf[dA + q * 4];
            unsigned int lo = (unsigned int)f2bf(a.x * b.x) | ((unsigned int)f2bf(a.y * b.y) << 16);
            unsigned int hi = (unsigned int)f2bf(a.z * b.z) | ((unsigned int)f2bf(a.w * b.w) << 16);
            *(uint2*)&h2w[eL * WST + q * 4] = make_uint2(lo, hi);
        }
        // phase 2: MFMA (A from own slice; compiler inserts lgkmcnt waits)
        frag_cd accA[6], accB[6];
        #pragma unroll
        for (int nt = 0; nt < 6; nt++) {
            accA[nt] = (frag_cd){0.f, 0.f, 0.f, 0.f};
            if (DUAL) accB[nt] = (frag_cd){0.f, 0.f, 0.f, 0.f};
        }
        #pragma unroll
        for (int kt = 0; kt < 3; kt++) {
            const int k0 = kt * 32 + quad * 8;
            frag_ab afrag = *(const frag_ab*)&h2w[lcol * WST + k0];
            #pragma unroll
            for (int nt = 0; nt < 6; nt++) {
                frag_ab bfragA = *(const frag_ab*)&W1t[(nt * 16 + lcol) * WST + k0];
                accA[nt] = __builtin_amdgcn_mfma_f32_16x16x32_bf16(afrag, bfragA, accA[nt], 0, 0, 0);
                if (DUAL) {
                    frag_ab bfragB = *(const frag_ab*)&W1t[96 * WST + (nt * 16 + lcol) * WST + k0];
                    accB[nt] = __builtin_amdgcn_mfma_f32_16x16x32_bf16(afrag, bfragB, accB[nt], 0, 0, 0);
                }
            }
        }
        // phase 3: +b1, prelu, dot W2, quad-reduce, tanh.  C/D: col=lcol, row=quad*4+reg.
        float psA[4] = {0.f, 0.f, 0.f, 0.f};
        float psB[4] = {0.f, 0.f, 0.f, 0.f};
        #pragma unroll
        for (int nt = 0; nt < 6; nt++) {
            float w2A = W2s[nt * 16 + lcol];
            float b1A = b1s[nt * 16 + lcol];
            #pragma unroll
            for (int reg = 0; reg < 4; reg++) {
                float u = accA[nt][reg] + b1A;
                u = u >= 0.f ? u : alphaA * u;
                psA[reg] += u * w2A;
            }
            if (DUAL) {
                float w2B = W2s[96 + nt * 16 + lcol];
                float b1B = b1s[96 + nt * 16 + lcol];
                #pragma unroll
                for (int reg = 0; reg < 4; reg++) {
                    float u = accB[nt][reg] + b1B;
                    u = u >= 0.f ? u : alphaB * u;
                    psB[reg] += u * w2B;
                }
            }
        }
        #pragma unroll
        for (int off = 1; off < 16; off <<= 1) {
            #pragma unroll
            for (int reg = 0; reg < 4; reg++) {
                psA[reg] += __shfl_xor(psA[reg], off, 64);
                if (DUAL) psB[reg] += __shfl_xor(psB[reg], off, 64);
            }
        }
        if (lcol == 0) {
            #pragma unroll
            for (int reg = 0; reg < 4; reg++) {
                int er = chunk * 16 + quad * 4 + reg;
                outA[er] = tanhf(psA[reg] + b2A);
                if (DUAL) outB[er] = tanhf(psB[reg] + b2B);
            }
        }
    }
}

// ---------------- CSR build: count / scan / scatter ----------------
__global__ __launch_bounds__(256) void count_kernel(
    const int* __restrict__ dst, int* __restrict__ cnt)
{
    int e = blockIdx.x * 256 + threadIdx.x;          // over E, exact
    atomicAdd(&cnt[dst[e]], 1);
}

// single block, 1024 threads; 25600 = 1024 * 25
__global__ __launch_bounds__(1024) void scan_kernel(
    const int* __restrict__ cnt, int* __restrict__ off, int* __restrict__ cur)
{
    __shared__ int part[1024];
    const int tid = threadIdx.x;
    const int base = tid * 25;
    int loc[25];
    int s = 0;
    #pragma unroll
    for (int i = 0; i < 25; i++) { loc[i] = s; s += cnt[base + i]; }
    part[tid] = s;
    __syncthreads();
    for (int d = 1; d < 1024; d <<= 1) {
        int t = (tid >= d) ? part[tid - d] : 0;
        __syncthreads();
        part[tid] += t;
        __syncthreads();
    }
    const int basesum = part[tid] - s;
    #pragma unroll
    for (int i = 0; i < 25; i++) {
        int o = basesum + loc[i];
        off[base + i] = o;
        cur[base + i] = o;
    }
    if (tid == 1023) off[N_NODES] = part[1023];
}

__global__ __launch_bounds__(256) void scatter_kernel(
    const int* __restrict__ dst, int* __restrict__ cur, int* __restrict__ perm)
{
    int e = blockIdx.x * 256 + threadIdx.x;          // over E, exact
    int p = atomicAdd(&cur[dst[e]], 1);
    perm[p] = e;
}

// ---------------- fused: z = segsum(x[src]*e, dst) ; x_next = prelu(BN(LN(z + xin))) ----------------
__global__ __launch_bounds__(128) void agg_norm_kernel(
    const float* __restrict__ xf, const int* __restrict__ srcg,
    const float* __restrict__ ef,
    const int* __restrict__ off, const int* __restrict__ perm,
    const float* __restrict__ xin,
    const float* __restrict__ lng, const float* __restrict__ lnb,
    const float* __restrict__ bng, const float* __restrict__ bnb,
    const float* __restrict__ bnrm, const float* __restrict__ bnrv,
    const float* __restrict__ acta, int layer,
    float* __restrict__ xout)
{
    __shared__ float red[128];
    const int n = blockIdx.x;
    const int tid = threadIdx.x;
    const int beg = off[n], end = off[n + 1];
    float v = 0.f;
    if (tid < 96) {
        for (int j = beg; j < end; j++) {
            const int e = perm[j];
            v += xf[srcg[e] * 96 + tid] * ef[e];
        }
        v += xin[n * 96 + tid];
    }
    red[tid] = (tid < 96) ? v : 0.f;
    __syncthreads();
    for (int sft = 64; sft > 0; sft >>= 1) {
        if (tid < sft) red[tid] += red[tid + sft];
        __syncthreads();
    }
    const float mean = red[0] * (1.f / 96.f);
    __syncthreads();
    const float d = (tid < 96) ? (v - mean) : 0.f;
    red[tid] = d * d;
    __syncthreads();
    for (int sft = 64; sft > 0; sft >>= 1) {
        if (tid < sft) red[tid] += red[tid + sft];
        __syncthreads();
    }
    const float rstd = rsqrtf(red[0] * (1.f / 96.f) + EPSV);
    if (tid < 96) {
        const int c = layer * 96 + tid;
        float y = d * rstd * lng[c] + lnb[c];
        y = (y - bnrm[c]) * rsqrtf(bnrv[c] + EPSV) * bng[c] + bnb[c];
        const float a = acta[layer];
        xout[n * 96 + tid] = y >= 0.f ? y : a * y;
    }
}

// ---------------- final: out[64-node tile] = hcat @ t2_w + t2_b  (MFMA, K=288 in 3x96) ----------------
__global__ __launch_bounds__(256) void final_mfma(
    const float* __restrict__ x0, const float* __restrict__ x1, const float* __restrict__ x2,
    const float* __restrict__ t2w, const float* __restrict__ t2b,
    float* __restrict__ out)
{
    __shared__ alignas(16) unsigned short As[64 * WST];
    __shared__ alignas(16) unsigned short Bs[128 * WST];

    const int tid  = threadIdx.x;
    const int lane = tid & 63;
    const int wv   = tid >> 6;
    const int quad = lane >> 4;
    const int lcol = lane & 15;
    const int node0 = blockIdx.x * 64;

    frag_cd acc[8];
    #pragma unroll
    for (int nt = 0; nt < 8; nt++) acc[nt] = (frag_cd){0.f, 0.f, 0.f, 0.f};

    for (int ck = 0; ck < 3; ck++) {
        const float* xc = (ck == 0) ? x0 : (ck == 1 ? x1 : x2);
        __syncthreads();
        #pragma unroll
        for (int r = 0; r < 6; r++) {
            int m = r * 256 + tid;
            int mm = m / 24, q = m - mm * 24;
            const float4 a = *(const float4*)&xc[(node0 + mm) * 96 + q * 4];
            unsigned int lo = (unsigned int)f2bf(a.x) | ((unsigned int)f2bf(a.y) << 16);
            unsigned int hi = (unsigned int)f2bf(a.z) | ((unsigned int)f2bf(a.w) << 16);
            *(uint2*)&As[mm * WST + q * 4] = make_uint2(lo, hi);
        }
        #pragma unroll
        for (int r = 0; r < 48; r++) {
            int idx = r * 256 + tid;
            int cc = idx >> 7, o = idx & 127;
            Bs[o * WST + cc] = f2bf(t2w[(ck * 96 + cc) * 128 + o]);
        }
        __syncthreads();
        const int mrow = wv * 16 + lcol;
        #pragma unroll
        for (int kt = 0; kt < 3; kt++) {
            const int k0 = kt * 32 + quad * 8;
            frag_ab afrag = *(const frag_ab*)&As[mrow * WST + k0];
            #pragma unroll
            for (int nt = 0; nt < 8; nt++) {
                frag_ab bfrag = *(const frag_ab*)&Bs[(nt * 16 + lcol) * WST + k0];
                acc[nt] = __builtin_amdgcn_mfma_f32_16x16x32_bf16(afrag, bfrag, acc[nt], 0, 0, 0);
            }
        }
    }
    const int node = node0 + wv * 16 + quad * 4;
    #pragma unroll
    for (int nt = 0; nt < 8; nt++) {
        const int o = nt * 16 + lcol;
        const float bias = t2b[o];
        #pragma unroll
        for (int reg = 0; reg < 4; reg++)
            out[(node + reg) * 128 + o] = acc[nt][reg] + bias;
    }
}

extern "C" void kernel_launch(void* const* d_in, const int* in_sizes, int n_in,
                              void* d_out, int out_size, void* d_ws, size_t ws_size,
                              hipStream_t stream)
{
    const float* h    = (const float*)d_in[0];
    const int*   src  = (const int*)d_in[1];
    const int*   dst  = (const int*)d_in[2];
    const float* tpw1 = (const float*)d_in[3];
    const float* tpb1 = (const float*)d_in[4];
    const float* tpa  = (const float*)d_in[5];
    const float* tpw2 = (const float*)d_in[6];
    const float* tpb2 = (const float*)d_in[7];
    const float* tmw1 = (const float*)d_in[8];
    const float* tmb1 = (const float*)d_in[9];
    const float* tma  = (const float*)d_in[10];
    const float* tmw2 = (const float*)d_in[11];
    const float* tmb2 = (const float*)d_in[12];
    const float* lng  = (const float*)d_in[13];
    const float* lnb  = (const float*)d_in[14];
    const float* bng  = (const float*)d_in[15];
    const float* bnb  = (const float*)d_in[16];
    const float* bnrm = (const float*)d_in[17];
    const float* bnrv = (const float*)d_in[18];
    const float* acta = (const float*)d_in[19];
    const float* gW1  = (const float*)d_in[20];
    const float* gb1  = (const float*)d_in[21];
    const float* ga   = (const float*)d_in[22];
    const float* gW2  = (const float*)d_in[23];
    const float* gb2  = (const float*)d_in[24];
    const float* t2w  = (const float*)d_in[25];
    const float* t2b  = (const float*)d_in[26];

    float* ws = (float*)d_ws;
    float* x0 = ws;                         // N*96
    float* x1 = x0 + N_NODES * 96;          // N*96
    float* x2 = x1 + N_NODES * 96;          // N*96
    float* eb = x2 + N_NODES * 96;          // E
    int* cnt  = (int*)(eb + N_EDGES);       // N
    int* off  = cnt + N_NODES;              // N+1
    int* cur  = off + N_NODES + 1;          // N
    int* perm = cur + N_NODES;              // E

    float* out = (float*)d_out;             // N*128 fp32
    float* ee  = out + N_NODES * 128;       // 2E fp32

    // ---- CSR build (dst-only; used by agg_norm) ----
    hipMemsetAsync(cnt, 0, N_NODES * sizeof(int), stream);
    count_kernel<<<N_EDGES / 256, 256, 0, stream>>>(dst, cnt);
    scan_kernel<<<1, 1024, 0, stream>>>(cnt, off, cur);
    scatter_kernel<<<N_EDGES / 256, 256, 0, stream>>>(dst, cur, perm);

    // ---- fused transform (t1+t2) ----
    transform_mfma<<<dim3(200, 2), 256, 0, stream>>>(
        h, tpw1, tpb1, tpa, tpw2, tpb2, tmw1, tmb1, tma, tmw2, tmb2, x0);

    // ---- layer 0 ----
    gate_kernel<false><<<1600, 256, 0, stream>>>(x0, src, dst, gW1, gb1, ga, gW2, gb2, 0, 0, eb, nullptr);
    agg_norm_kernel<<<N_NODES, 128, 0, stream>>>(x0, src, eb, off, perm, x0,
        lng, lnb, bng, bnb, bnrm, bnrv, acta, 0, x1);

    // ---- fused: es[layer0](x1) -> ee   AND   agg-gate[layer1](x1) -> eb ----
    gate_kernel<true><<<1600, 256, 0, stream>>>(x1, src, dst, gW1, gb1, ga, gW2, gb2, 0, 1, ee, eb);

    // ---- layer 1 ----
    agg_norm_kernel<<<N_NODES, 128, 0, stream>>>(x1, src, eb, off, perm, x1,
        lng, lnb, bng, bnb, bnrm, bnrv, acta, 1, x2);
    gate_kernel<false><<<1600, 256, 0, stream>>>(x2, src, dst, gW1, gb1, ga, gW2, gb2, 1, 0, ee + N_EDGES, nullptr);

    // ---- readout ----
    final_mfma<<<N_NODES / 64, 256, 0, stream>>>(x0, x1, x2, t2w, t2b, out);
}

// Round 12
// 508.487 us; speedup vs baseline: 1.2745x; 1.2745x over previous
//
#include <hip/hip_runtime.h>

#define N_NODES 25600
#define N_EDGES 409600
#define EPSV 1e-5f

__device__ __forceinline__ unsigned short f2bf(float f) {
    unsigned int x = __float_as_uint(f);
    x += 0x7fffu + ((x >> 16) & 1u);
    return (unsigned short)(x >> 16);
}
// packed 2x f32 -> bf16x2 in one instruction where available (gfx950: v_cvt_pk_bf16_f32)
__device__ __forceinline__ unsigned int f2bf2(float a, float b) {
#if __has_builtin(__builtin_amdgcn_cvt_pk_bf16_f32)
    auto r = __builtin_amdgcn_cvt_pk_bf16_f32(a, b);
    unsigned int u;
    __builtin_memcpy(&u, &r, 4);
    return u;
#else
    return (unsigned int)f2bf(a) | ((unsigned int)f2bf(b) << 16);
#endif
}

using frag_ab = __attribute__((ext_vector_type(8))) short;  // 8 bf16 = 4 VGPRs
using frag_cd = __attribute__((ext_vector_type(4))) float;

#define WST 104   // gate/final LDS row stride (bf16): 208 B, 16B-aligned, non-pow-2
#define TWST 72   // transform weight LDS stride (bf16)
#define THST 200  // transform h/y1 LDS stride (bf16)

// ---------------- fused transform: x[n,0:96] = W2g·prelu(W1g·h[n]+b1)+b2, grouped, MFMA ----------------
__global__ __launch_bounds__(256) void transform_mfma(
    const float* __restrict__ h,
    const float* __restrict__ tpw1, const float* __restrict__ tpb1, const float* __restrict__ tpa,
    const float* __restrict__ tpw2, const float* __restrict__ tpb2,
    const float* __restrict__ tmw1, const float* __restrict__ tmb1, const float* __restrict__ tma,
    const float* __restrict__ tmw2, const float* __restrict__ tmb2,
    float* __restrict__ xout)
{
    __shared__ alignas(16) unsigned short W1s[192 * TWST]; // [o][i] bf16
    __shared__ alignas(16) unsigned short W2s[96 * TWST];  // [o][i] bf16
    __shared__ alignas(16) unsigned short hs[64 * THST];   // [m][c] bf16; y1 overwrites in place
    __shared__ float b1s[192];
    __shared__ float b2s[96];

    const int tid = threadIdx.x;
    const int s = blockIdx.y;
    const float* w1 = s ? tmw1 : tpw1;
    const float* b1 = s ? tmb1 : tpb1;
    const float* w2 = s ? tmw2 : tpw2;
    const float* b2 = s ? tmb2 : tpb2;
    const float alpha = (s ? tma : tpa)[0];

    #pragma unroll
    for (int r = 0; r < 12; r++) {
        int idx4 = r * 256 + tid;                    // over 192*16
        int o = idx4 >> 4, i4 = (idx4 & 15) * 4;
        const float4 a = *(const float4*)&w1[o * 64 + i4];
        *(uint2*)&W1s[o * TWST + i4] = make_uint2(f2bf2(a.x, a.y), f2bf2(a.z, a.w));
    }
    #pragma unroll
    for (int r = 0; r < 6; r++) {
        int idx4 = r * 256 + tid;                    // over 96*16
        int o = idx4 >> 4, i4 = (idx4 & 15) * 4;
        const float4 a = *(const float4*)&w2[o * 64 + i4];
        *(uint2*)&W2s[o * TWST + i4] = make_uint2(f2bf2(a.x, a.y), f2bf2(a.z, a.w));
    }
    if (tid < 192) b1s[tid] = b1[tid];
    if (tid < 96) b2s[tid] = b2[tid];
    __syncthreads();

    const int lane = tid & 63;
    const int wv = tid >> 6;
    const int quad = lane >> 4;
    const int lcol = lane & 15;
    const int m0 = wv * 16;
    const int j0 = blockIdx.x * 64;

    #pragma unroll
    for (int r = 0; r < 12; r++) {
        int idx = r * 256 + tid;                     // over 64*48 float4s
        int m = idx / 48, q = idx - m * 48;
        const float4 a = *(const float4*)&h[(2 * (j0 + m) + s) * 192 + q * 4];
        *(uint2*)&hs[m * THST + q * 4] = make_uint2(f2bf2(a.x, a.y), f2bf2(a.z, a.w));
    }
    __syncthreads();

    const int arow = (m0 + lcol) * THST;
    #pragma unroll
    for (int g = 0; g < 3; g++) {
        frag_cd acc[4];
        #pragma unroll
        for (int nt = 0; nt < 4; nt++) acc[nt] = (frag_cd){0.f, 0.f, 0.f, 0.f};
        #pragma unroll
        for (int kt = 0; kt < 2; kt++) {
            const int k0 = kt * 32 + quad * 8;
            frag_ab af = *(const frag_ab*)&hs[arow + g * 64 + k0];
            #pragma unroll
            for (int nt = 0; nt < 4; nt++) {
                frag_ab bf = *(const frag_ab*)&W1s[(g * 64 + nt * 16 + lcol) * TWST + k0];
                acc[nt] = __builtin_amdgcn_mfma_f32_16x16x32_bf16(af, bf, acc[nt], 0, 0, 0);
            }
        }
        #pragma unroll
        for (int nt = 0; nt < 4; nt++) {
            const int o = g * 64 + nt * 16 + lcol;
            const float bv = b1s[o];
            #pragma unroll
            for (int reg = 0; reg < 4; reg++) {
                float u = acc[nt][reg] + bv;
                u = u >= 0.f ? u : alpha * u;
                hs[(m0 + quad * 4 + reg) * THST + o] = f2bf(u);
            }
        }
    }
    #pragma unroll
    for (int g2 = 0; g2 < 3; g2++) {
        frag_cd acc[2];
        acc[0] = (frag_cd){0.f, 0.f, 0.f, 0.f};
        acc[1] = (frag_cd){0.f, 0.f, 0.f, 0.f};
        #pragma unroll
        for (int kt = 0; kt < 2; kt++) {
            const int k0 = kt * 32 + quad * 8;
            frag_ab af = *(const frag_ab*)&hs[arow + g2 * 64 + k0];
            #pragma unroll
            for (int nt = 0; nt < 2; nt++) {
                frag_ab bf = *(const frag_ab*)&W2s[(g2 * 32 + nt * 16 + lcol) * TWST + k0];
                acc[nt] = __builtin_amdgcn_mfma_f32_16x16x32_bf16(af, bf, acc[nt], 0, 0, 0);
            }
        }
        #pragma unroll
        for (int nt = 0; nt < 2; nt++) {
            const int o2 = g2 * 32 + nt * 16 + lcol;
            const float bv = b2s[o2];
            #pragma unroll
            for (int reg = 0; reg < 4; reg++) {
                const int node = 2 * (j0 + m0 + quad * 4 + reg) + s;
                xout[node * 96 + o2] = acc[nt][reg] + bv;
            }
        }
    }
}

// ---------------- gate (MFMA): e = tanh(prelu((x[dst]*x[src]) @ W1 + b1) @ W2 + b2) ----------------
// R7-best structure: 64-edge block tiles, W1 in LDS, coalesced row gather through LDS.
// Micro-opts: all 4 tiles' indices staged once in the prologue (one barrier saved per
// tile), packed v_cvt_pk_bf16_f32 conversions. Grid MUST be 1600 (4 tiles per block).
template<bool DUAL>
__global__ __launch_bounds__(256) void gate_kernel(
    const float* __restrict__ xf,
    const int* __restrict__ src, const int* __restrict__ dst,
    const float* __restrict__ gW1, const float* __restrict__ gb1,
    const float* __restrict__ ga,  const float* __restrict__ gW2,
    const float* __restrict__ gb2, int layerA, int layerB,
    float* __restrict__ outA, float* __restrict__ outB)
{
    __shared__ alignas(16) unsigned short W1t[(DUAL ? 2 : 1) * 96 * WST]; // [n][k] bf16
    __shared__ alignas(16) unsigned short h2s[64 * WST];                  // [edge][k] bf16
    __shared__ float W2s[(DUAL ? 2 : 1) * 96];
    __shared__ float b1s[(DUAL ? 2 : 1) * 96];
    __shared__ int ssrc4[256];
    __shared__ int sdst4[256];

    const int tid = threadIdx.x;
    {
        const float* W1p = gW1 + layerA * 9216;
        for (int idx = tid; idx < 9216; idx += 256) {
            int k = idx / 96, n = idx - k * 96;
            W1t[n * WST + k] = f2bf(W1p[idx]);
        }
        if (DUAL) {
            const float* W1q = gW1 + layerB * 9216;
            for (int idx = tid; idx < 9216; idx += 256) {
                int k = idx / 96, n = idx - k * 96;
                W1t[96 * WST + n * WST + k] = f2bf(W1q[idx]);
            }
        }
        // stage all 4 tiles' edge indices: thread i -> tile i>>6, slot i&63
        int e = (blockIdx.x + (tid >> 6) * 1600) * 64 + (tid & 63);
        ssrc4[tid] = src[e];
        sdst4[tid] = dst[e];
    }
    if (tid < 96) {
        W2s[tid] = gW2[layerA * 96 + tid];
        b1s[tid] = gb1[layerA * 96 + tid];
        if (DUAL) {
            W2s[96 + tid] = gW2[layerB * 96 + tid];
            b1s[96 + tid] = gb1[layerB * 96 + tid];
        }
    }
    const float alphaA = ga[layerA];
    const float b2A = gb2[layerA];
    const float alphaB = DUAL ? ga[layerB] : 0.f;
    const float b2B = DUAL ? gb2[layerB] : 0.f;
    __syncthreads();

    const int lane = tid & 63;
    const int wv   = tid >> 6;
    const int quad = lane >> 4;
    const int lcol = lane & 15;
    const int m0   = wv * 16;

    #pragma unroll 1
    for (int t = 0; t < 4; t++) {
        const int base = (blockIdx.x + t * 1600) * 64;
        const int* ss = &ssrc4[t * 64];
        const int* sd = &sdst4[t * 64];
        // phase 1: h2 = x[src]*x[dst], coalesced float4 row gather -> packed bf16 -> LDS
        #pragma unroll
        for (int r = 0; r < 6; r++) {
            int m = r * 256 + tid;                   // over 64 edges x 24 float4s
            int eL = m / 24, q = m - eL * 24;
            const float4 a = *(const float4*)&xf[ss[eL] * 96 + q * 4];
            const float4 b = *(const float4*)&xf[sd[eL] * 96 + q * 4];
            *(uint2*)&h2s[eL * WST + q * 4] =
                make_uint2(f2bf2(a.x * b.x, a.y * b.y), f2bf2(a.z * b.z, a.w * b.w));
        }
        __syncthreads();

        // phase 2: MFMA (A[m=lcol][k=quad*8+j] from h2s, B[n=lcol][k] from W1t)
        frag_cd accA[6], accB[6];
        #pragma unroll
        for (int nt = 0; nt < 6; nt++) {
            accA[nt] = (frag_cd){0.f, 0.f, 0.f, 0.f};
            if (DUAL) accB[nt] = (frag_cd){0.f, 0.f, 0.f, 0.f};
        }
        const int mrow = m0 + lcol;
        #pragma unroll
        for (int kt = 0; kt < 3; kt++) {
            const int k0 = kt * 32 + quad * 8;
            frag_ab afrag = *(const frag_ab*)&h2s[mrow * WST + k0];
            #pragma unroll
            for (int nt = 0; nt < 6; nt++) {
                frag_ab bfragA = *(const frag_ab*)&W1t[(nt * 16 + lcol) * WST + k0];
                accA[nt] = __builtin_amdgcn_mfma_f32_16x16x32_bf16(afrag, bfragA, accA[nt], 0, 0, 0);
                if (DUAL) {
                    frag_ab bfragB = *(const frag_ab*)&W1t[96 * WST + (nt * 16 + lcol) * WST + k0];
                    accB[nt] = __builtin_amdgcn_mfma_f32_16x16x32_bf16(afrag, bfragB, accB[nt], 0, 0, 0);
                }
            }
        }
        // phase 3: +b1, prelu, dot W2, quad-reduce, tanh.  C/D: col=lcol, row=quad*4+reg.
        float psA[4] = {0.f, 0.f, 0.f, 0.f};
        float psB[4] = {0.f, 0.f, 0.f, 0.f};
        #pragma unroll
        for (int nt = 0; nt < 6; nt++) {
            float w2A = W2s[nt * 16 + lcol];
            float b1A = b1s[nt * 16 + lcol];
            #pragma unroll
            for (int reg = 0; reg < 4; reg++) {
                float u = accA[nt][reg] + b1A;
                u = u >= 0.f ? u : alphaA * u;
                psA[reg] += u * w2A;
            }
            if (DUAL) {
                float w2B = W2s[96 + nt * 16 + lcol];
                float b1B = b1s[96 + nt * 16 + lcol];
                #pragma unroll
                for (int reg = 0; reg < 4; reg++) {
                    float u = accB[nt][reg] + b1B;
                    u = u >= 0.f ? u : alphaB * u;
                    psB[reg] += u * w2B;
                }
            }
        }
        #pragma unroll
        for (int off = 1; off < 16; off <<= 1) {
            #pragma unroll
            for (int reg = 0; reg < 4; reg++) {
                psA[reg] += __shfl_xor(psA[reg], off, 64);
                if (DUAL) psB[reg] += __shfl_xor(psB[reg], off, 64);
            }
        }
        if (lcol == 0) {
            #pragma unroll
            for (int reg = 0; reg < 4; reg++) {
                int er = base + m0 + quad * 4 + reg;
                outA[er] = tanhf(psA[reg] + b2A);
                if (DUAL) outB[er] = tanhf(psB[reg] + b2B);
            }
        }
        __syncthreads();
    }
}

// ---------------- CSR build: count / scan / scatter ----------------
__global__ __launch_bounds__(256) void count_kernel(
    const int* __restrict__ dst, int* __restrict__ cnt)
{
    int e = blockIdx.x * 256 + threadIdx.x;          // over E, exact
    atomicAdd(&cnt[dst[e]], 1);
}

// single block, 1024 threads; 25600 = 1024 * 25
__global__ __launch_bounds__(1024) void scan_kernel(
    const int* __restrict__ cnt, int* __restrict__ off, int* __restrict__ cur)
{
    __shared__ int part[1024];
    const int tid = threadIdx.x;
    const int base = tid * 25;
    int loc[25];
    int s = 0;
    #pragma unroll
    for (int i = 0; i < 25; i++) { loc[i] = s; s += cnt[base + i]; }
    part[tid] = s;
    __syncthreads();
    for (int d = 1; d < 1024; d <<= 1) {
        int t = (tid >= d) ? part[tid - d] : 0;
        __syncthreads();
        part[tid] += t;
        __syncthreads();
    }
    const int basesum = part[tid] - s;
    #pragma unroll
    for (int i = 0; i < 25; i++) {
        int o = basesum + loc[i];
        off[base + i] = o;
        cur[base + i] = o;
    }
    if (tid == 1023) off[N_NODES] = part[1023];
}

__global__ __launch_bounds__(256) void scatter_kernel(
    const int* __restrict__ dst, int* __restrict__ cur, int* __restrict__ perm)
{
    int e = blockIdx.x * 256 + threadIdx.x;          // over E, exact
    int p = atomicAdd(&cur[dst[e]], 1);
    perm[p] = e;
}

// ---------------- fused: z = segsum(x[src]*e, dst) ; x_next = prelu(BN(LN(z + xin))) ----------------
__global__ __launch_bounds__(128) void agg_norm_kernel(
    const float* __restrict__ xf, const int* __restrict__ srcg,
    const float* __restrict__ ef,
    const int* __restrict__ off, const int* __restrict__ perm,
    const float* __restrict__ xin,
    const float* __restrict__ lng, const float* __restrict__ lnb,
    const float* __restrict__ bng, const float* __restrict__ bnb,
    const float* __restrict__ bnrm, const float* __restrict__ bnrv,
    const float* __restrict__ acta, int layer,
    float* __restrict__ xout)
{
    __shared__ float red[128];
    const int n = blockIdx.x;
    const int tid = threadIdx.x;
    const int beg = off[n], end = off[n + 1];
    float v = 0.f;
    if (tid < 96) {
        // unroll x4: 4 independent perm->src->row load chains in flight
        float v0 = 0.f, v1 = 0.f, v2 = 0.f, v3 = 0.f;
        int j = beg;
        for (; j + 4 <= end; j += 4) {
            const int e0 = perm[j],     e1 = perm[j + 1];
            const int e2 = perm[j + 2], e3 = perm[j + 3];
            v0 += xf[srcg[e0] * 96 + tid] * ef[e0];
            v1 += xf[srcg[e1] * 96 + tid] * ef[e1];
            v2 += xf[srcg[e2] * 96 + tid] * ef[e2];
            v3 += xf[srcg[e3] * 96 + tid] * ef[e3];
        }
        for (; j < end; j++) {
            const int e = perm[j];
            v0 += xf[srcg[e] * 96 + tid] * ef[e];
        }
        v = ((v0 + v1) + (v2 + v3)) + xin[n * 96 + tid];
    }
    red[tid] = (tid < 96) ? v : 0.f;
    __syncthreads();
    for (int sft = 64; sft > 0; sft >>= 1) {
        if (tid < sft) red[tid] += red[tid + sft];
        __syncthreads();
    }
    const float mean = red[0] * (1.f / 96.f);
    __syncthreads();
    const float d = (tid < 96) ? (v - mean) : 0.f;
    red[tid] = d * d;
    __syncthreads();
    for (int sft = 64; sft > 0; sft >>= 1) {
        if (tid < sft) red[tid] += red[tid + sft];
        __syncthreads();
    }
    const float rstd = rsqrtf(red[0] * (1.f / 96.f) + EPSV);
    if (tid < 96) {
        const int c = layer * 96 + tid;
        float y = d * rstd * lng[c] + lnb[c];
        y = (y - bnrm[c]) * rsqrtf(bnrv[c] + EPSV) * bng[c] + bnb[c];
        const float a = acta[layer];
        xout[n * 96 + tid] = y >= 0.f ? y : a * y;
    }
}

// ---------------- final: out[64-node tile] = hcat @ t2_w + t2_b  (MFMA, K=288 in 3x96) ----------------
__global__ __launch_bounds__(256) void final_mfma(
    const float* __restrict__ x0, const float* __restrict__ x1, const float* __restrict__ x2,
    const float* __restrict__ t2w, const float* __restrict__ t2b,
    float* __restrict__ out)
{
    __shared__ alignas(16) unsigned short As[64 * WST];
    __shared__ alignas(16) unsigned short Bs[128 * WST];

    const int tid  = threadIdx.x;
    const int lane = tid & 63;
    const int wv   = tid >> 6;
    const int quad = lane >> 4;
    const int lcol = lane & 15;
    const int node0 = blockIdx.x * 64;

    frag_cd acc[8];
    #pragma unroll
    for (int nt = 0; nt < 8; nt++) acc[nt] = (frag_cd){0.f, 0.f, 0.f, 0.f};

    for (int ck = 0; ck < 3; ck++) {
        const float* xc = (ck == 0) ? x0 : (ck == 1 ? x1 : x2);
        __syncthreads();
        #pragma unroll
        for (int r = 0; r < 6; r++) {
            int m = r * 256 + tid;
            int mm = m / 24, q = m - mm * 24;
            const float4 a = *(const float4*)&xc[(node0 + mm) * 96 + q * 4];
            *(uint2*)&As[mm * WST + q * 4] = make_uint2(f2bf2(a.x, a.y), f2bf2(a.z, a.w));
        }
        #pragma unroll
        for (int r = 0; r < 48; r++) {
            int idx = r * 256 + tid;
            int cc = idx >> 7, o = idx & 127;
            Bs[o * WST + cc] = f2bf(t2w[(ck * 96 + cc) * 128 + o]);
        }
        __syncthreads();
        const int mrow = wv * 16 + lcol;
        #pragma unroll
        for (int kt = 0; kt < 3; kt++) {
            const int k0 = kt * 32 + quad * 8;
            frag_ab afrag = *(const frag_ab*)&As[mrow * WST + k0];
            #pragma unroll
            for (int nt = 0; nt < 8; nt++) {
                frag_ab bfrag = *(const frag_ab*)&Bs[(nt * 16 + lcol) * WST + k0];
                acc[nt] = __builtin_amdgcn_mfma_f32_16x16x32_bf16(afrag, bfrag, acc[nt], 0, 0, 0);
            }
        }
    }
    const int node = node0 + wv * 16 + quad * 4;
    #pragma unroll
    for (int nt = 0; nt < 8; nt++) {
        const int o = nt * 16 + lcol;
        const float bias = t2b[o];
        #pragma unroll
        for (int reg = 0; reg < 4; reg++)
            out[(node + reg) * 128 + o] = acc[nt][reg] + bias;
    }
}

extern "C" void kernel_launch(void* const* d_in, const int* in_sizes, int n_in,
                              void* d_out, int out_size, void* d_ws, size_t ws_size,
                              hipStream_t stream)
{
    const float* h    = (const float*)d_in[0];
    const int*   src  = (const int*)d_in[1];
    const int*   dst  = (const int*)d_in[2];
    const float* tpw1 = (const float*)d_in[3];
    const float* tpb1 = (const float*)d_in[4];
    const float* tpa  = (const float*)d_in[5];
    const float* tpw2 = (const float*)d_in[6];
    const float* tpb2 = (const float*)d_in[7];
    const float* tmw1 = (const float*)d_in[8];
    const float* tmb1 = (const float*)d_in[9];
    const float* tma  = (const float*)d_in[10];
    const float* tmw2 = (const float*)d_in[11];
    const float* tmb2 = (const float*)d_in[12];
    const float* lng  = (const float*)d_in[13];
    const float* lnb  = (const float*)d_in[14];
    const float* bng  = (const float*)d_in[15];
    const float* bnb  = (const float*)d_in[16];
    const float* bnrm = (const float*)d_in[17];
    const float* bnrv = (const float*)d_in[18];
    const float* acta = (const float*)d_in[19];
    const float* gW1  = (const float*)d_in[20];
    const float* gb1  = (const float*)d_in[21];
    const float* ga   = (const float*)d_in[22];
    const float* gW2  = (const float*)d_in[23];
    const float* gb2  = (const float*)d_in[24];
    const float* t2w  = (const float*)d_in[25];
    const float* t2b  = (const float*)d_in[26];

    float* ws = (float*)d_ws;
    float* x0 = ws;                         // N*96
    float* x1 = x0 + N_NODES * 96;          // N*96
    float* x2 = x1 + N_NODES * 96;          // N*96
    float* eb = x2 + N_NODES * 96;          // E
    int* cnt  = (int*)(eb + N_EDGES);       // N
    int* off  = cnt + N_NODES;              // N+1
    int* cur  = off + N_NODES + 1;          // N
    int* perm = cur + N_NODES;              // E

    float* out = (float*)d_out;             // N*128 fp32
    float* ee  = out + N_NODES * 128;       // 2E fp32

    // ---- CSR build (dst-only; used by agg_norm) ----
    hipMemsetAsync(cnt, 0, N_NODES * sizeof(int), stream);
    count_kernel<<<N_EDGES / 256, 256, 0, stream>>>(dst, cnt);
    scan_kernel<<<1, 1024, 0, stream>>>(cnt, off, cur);
    scatter_kernel<<<N_EDGES / 256, 256, 0, stream>>>(dst, cur, perm);

    // ---- fused transform (t1+t2) ----
    transform_mfma<<<dim3(200, 2), 256, 0, stream>>>(
        h, tpw1, tpb1, tpa, tpw2, tpb2, tmw1, tmb1, tma, tmw2, tmb2, x0);

    // ---- layer 0 ----
    gate_kernel<false><<<1600, 256, 0, stream>>>(x0, src, dst, gW1, gb1, ga, gW2, gb2, 0, 0, eb, nullptr);
    agg_norm_kernel<<<N_NODES, 128, 0, stream>>>(x0, src, eb, off, perm, x0,
        lng, lnb, bng, bnb, bnrm, bnrv, acta, 0, x1);

    // ---- fused: es[layer0](x1) -> ee   AND   agg-gate[layer1](x1) -> eb ----
    gate_kernel<true><<<1600, 256, 0, stream>>>(x1, src, dst, gW1, gb1, ga, gW2, gb2, 0, 1, ee, eb);

    // ---- layer 1 ----
    agg_norm_kernel<<<N_NODES, 128, 0, stream>>>(x1, src, eb, off, perm, x1,
        lng, lnb, bng, bnb, bnrm, bnrv, acta, 1, x2);
    gate_kernel<false><<<1600, 256, 0, stream>>>(x2, src, dst, gW1, gb1, ga, gW2, gb2, 1, 0, ee + N_EDGES, nullptr);

    // ---- readout ----
    final_mfma<<<N_NODES / 64, 256, 0, stream>>>(x0, x1, x2, t2w, t2b, out);
}

// Round 13
// 503.026 us; speedup vs baseline: 1.2883x; 1.0109x over previous
//
#include <hip/hip_runtime.h>

#define N_NODES 25600
#define N_EDGES 409600
#define EPSV 1e-5f

__device__ __forceinline__ unsigned short f2bf(float f) {
    unsigned int x = __float_as_uint(f);
    x += 0x7fffu + ((x >> 16) & 1u);
    return (unsigned short)(x >> 16);
}
// packed 2x f32 -> bf16x2 in one instruction where available (gfx950: v_cvt_pk_bf16_f32)
__device__ __forceinline__ unsigned int f2bf2(float a, float b) {
#if __has_builtin(__builtin_amdgcn_cvt_pk_bf16_f32)
    auto r = __builtin_amdgcn_cvt_pk_bf16_f32(a, b);
    unsigned int u;
    __builtin_memcpy(&u, &r, 4);
    return u;
#else
    return (unsigned int)f2bf(a) | ((unsigned int)f2bf(b) << 16);
#endif
}

using frag_ab = __attribute__((ext_vector_type(8))) short;  // 8 bf16 = 4 VGPRs
using frag_cd = __attribute__((ext_vector_type(4))) float;

#define WST 104   // h2s/final LDS row stride (bf16): 208 B, 16B-aligned; A-read aliasing 2-way = free
#define TWST 72   // transform weight LDS stride (bf16)
#define THST 200  // transform h/y1 LDS stride (bf16)

// ---------------- fused transform: x[n,0:96] = W2g·prelu(W1g·h[n]+b1)+b2, grouped, MFMA ----------------
__global__ __launch_bounds__(256) void transform_mfma(
    const float* __restrict__ h,
    const float* __restrict__ tpw1, const float* __restrict__ tpb1, const float* __restrict__ tpa,
    const float* __restrict__ tpw2, const float* __restrict__ tpb2,
    const float* __restrict__ tmw1, const float* __restrict__ tmb1, const float* __restrict__ tma,
    const float* __restrict__ tmw2, const float* __restrict__ tmb2,
    float* __restrict__ xout)
{
    __shared__ alignas(16) unsigned short W1s[192 * TWST]; // [o][i] bf16
    __shared__ alignas(16) unsigned short W2s[96 * TWST];  // [o][i] bf16
    __shared__ alignas(16) unsigned short hs[64 * THST];   // [m][c] bf16; y1 overwrites in place
    __shared__ float b1s[192];
    __shared__ float b2s[96];

    const int tid = threadIdx.x;
    const int s = blockIdx.y;
    const float* w1 = s ? tmw1 : tpw1;
    const float* b1 = s ? tmb1 : tpb1;
    const float* w2 = s ? tmw2 : tpw2;
    const float* b2 = s ? tmb2 : tpb2;
    const float alpha = (s ? tma : tpa)[0];

    #pragma unroll
    for (int r = 0; r < 12; r++) {
        int idx4 = r * 256 + tid;                    // over 192*16
        int o = idx4 >> 4, i4 = (idx4 & 15) * 4;
        const float4 a = *(const float4*)&w1[o * 64 + i4];
        *(uint2*)&W1s[o * TWST + i4] = make_uint2(f2bf2(a.x, a.y), f2bf2(a.z, a.w));
    }
    #pragma unroll
    for (int r = 0; r < 6; r++) {
        int idx4 = r * 256 + tid;                    // over 96*16
        int o = idx4 >> 4, i4 = (idx4 & 15) * 4;
        const float4 a = *(const float4*)&w2[o * 64 + i4];
        *(uint2*)&W2s[o * TWST + i4] = make_uint2(f2bf2(a.x, a.y), f2bf2(a.z, a.w));
    }
    if (tid < 192) b1s[tid] = b1[tid];
    if (tid < 96) b2s[tid] = b2[tid];
    __syncthreads();

    const int lane = tid & 63;
    const int wv = tid >> 6;
    const int quad = lane >> 4;
    const int lcol = lane & 15;
    const int m0 = wv * 16;
    const int j0 = blockIdx.x * 64;

    #pragma unroll
    for (int r = 0; r < 12; r++) {
        int idx = r * 256 + tid;                     // over 64*48 float4s
        int m = idx / 48, q = idx - m * 48;
        const float4 a = *(const float4*)&h[(2 * (j0 + m) + s) * 192 + q * 4];
        *(uint2*)&hs[m * THST + q * 4] = make_uint2(f2bf2(a.x, a.y), f2bf2(a.z, a.w));
    }
    __syncthreads();

    const int arow = (m0 + lcol) * THST;
    #pragma unroll
    for (int g = 0; g < 3; g++) {
        frag_cd acc[4];
        #pragma unroll
        for (int nt = 0; nt < 4; nt++) acc[nt] = (frag_cd){0.f, 0.f, 0.f, 0.f};
        #pragma unroll
        for (int kt = 0; kt < 2; kt++) {
            const int k0 = kt * 32 + quad * 8;
            frag_ab af = *(const frag_ab*)&hs[arow + g * 64 + k0];
            #pragma unroll
            for (int nt = 0; nt < 4; nt++) {
                frag_ab bf = *(const frag_ab*)&W1s[(g * 64 + nt * 16 + lcol) * TWST + k0];
                acc[nt] = __builtin_amdgcn_mfma_f32_16x16x32_bf16(af, bf, acc[nt], 0, 0, 0);
            }
        }
        #pragma unroll
        for (int nt = 0; nt < 4; nt++) {
            const int o = g * 64 + nt * 16 + lcol;
            const float bv = b1s[o];
            #pragma unroll
            for (int reg = 0; reg < 4; reg++) {
                float u = acc[nt][reg] + bv;
                u = u >= 0.f ? u : alpha * u;
                hs[(m0 + quad * 4 + reg) * THST + o] = f2bf(u);
            }
        }
    }
    #pragma unroll
    for (int g2 = 0; g2 < 3; g2++) {
        frag_cd acc[2];
        acc[0] = (frag_cd){0.f, 0.f, 0.f, 0.f};
        acc[1] = (frag_cd){0.f, 0.f, 0.f, 0.f};
        #pragma unroll
        for (int kt = 0; kt < 2; kt++) {
            const int k0 = kt * 32 + quad * 8;
            frag_ab af = *(const frag_ab*)&hs[arow + g2 * 64 + k0];
            #pragma unroll
            for (int nt = 0; nt < 2; nt++) {
                frag_ab bf = *(const frag_ab*)&W2s[(g2 * 32 + nt * 16 + lcol) * TWST + k0];
                acc[nt] = __builtin_amdgcn_mfma_f32_16x16x32_bf16(af, bf, acc[nt], 0, 0, 0);
            }
        }
        #pragma unroll
        for (int nt = 0; nt < 2; nt++) {
            const int o2 = g2 * 32 + nt * 16 + lcol;
            const float bv = b2s[o2];
            #pragma unroll
            for (int reg = 0; reg < 4; reg++) {
                const int node = 2 * (j0 + m0 + quad * 4 + reg) + s;
                xout[node * 96 + o2] = acc[nt][reg] + bv;
            }
        }
    }
}

// ---------------- gate (MFMA): e = tanh(prelu((x[dst]*x[src]) @ W1 + b1) @ W2 + b2) ----------------
// R12 structure + FRAGMENT-MAJOR W1 in LDS: W1f[nt][kt][quad][lcol] as 16B frags ->
// every B-read is a lane-contiguous 1KB block (conflict-free), and no padding needed
// (18.4 KB/layer). LDS: single ~35 KB (4 blocks/CU), dual ~52.5 KB (3 blocks/CU).
template<bool DUAL>
__global__ __launch_bounds__(256) void gate_kernel(
    const float* __restrict__ xf,
    const int* __restrict__ src, const int* __restrict__ dst,
    const float* __restrict__ gW1, const float* __restrict__ gb1,
    const float* __restrict__ ga,  const float* __restrict__ gW2,
    const float* __restrict__ gb2, int layerA, int layerB,
    float* __restrict__ outA, float* __restrict__ outB)
{
    // frag-major: entry f = ((nt*3+kt)*4+quad)*16+lcol holds B[n=nt*16+lcol][k=kt*32+quad*8 ..+8]
    __shared__ alignas(16) unsigned short W1f[(DUAL ? 2 : 1) * 9216];
    __shared__ alignas(16) unsigned short h2s[64 * WST];    // [edge][k] bf16
    __shared__ float W2s[(DUAL ? 2 : 1) * 96];
    __shared__ float b1s[(DUAL ? 2 : 1) * 96];
    __shared__ int ssrc4[256];
    __shared__ int sdst4[256];

    const int tid = threadIdx.x;
    {
        // coalesced global read, frag-major LDS write (one-time)
        const float* W1p = gW1 + layerA * 9216;
        const float* W1q = gW1 + layerB * 9216;
        for (int idx = tid; idx < 9216; idx += 256) {
            int k = idx / 96, n = idx - k * 96;
            int kt = k >> 5, quad = (k & 31) >> 3, j = k & 7;
            int nt = n >> 4, lc = n & 15;
            int f = ((nt * 3 + kt) * 4 + quad) * 16 + lc;
            W1f[f * 8 + j] = f2bf(W1p[idx]);
            if (DUAL) W1f[9216 + f * 8 + j] = f2bf(W1q[idx]);
        }
        // stage all 4 tiles' edge indices: thread i -> tile i>>6, slot i&63
        int e = (blockIdx.x + (tid >> 6) * 1600) * 64 + (tid & 63);
        ssrc4[tid] = src[e];
        sdst4[tid] = dst[e];
    }
    if (tid < 96) {
        W2s[tid] = gW2[layerA * 96 + tid];
        b1s[tid] = gb1[layerA * 96 + tid];
        if (DUAL) {
            W2s[96 + tid] = gW2[layerB * 96 + tid];
            b1s[96 + tid] = gb1[layerB * 96 + tid];
        }
    }
    const float alphaA = ga[layerA];
    const float b2A = gb2[layerA];
    const float alphaB = DUAL ? ga[layerB] : 0.f;
    const float b2B = DUAL ? gb2[layerB] : 0.f;
    __syncthreads();

    const int lane = tid & 63;
    const int wv   = tid >> 6;
    const int quad = lane >> 4;
    const int lcol = lane & 15;
    const int m0   = wv * 16;

    #pragma unroll 1
    for (int t = 0; t < 4; t++) {
        const int base = (blockIdx.x + t * 1600) * 64;
        const int* ss = &ssrc4[t * 64];
        const int* sd = &sdst4[t * 64];
        // phase 1: h2 = x[src]*x[dst], coalesced float4 row gather -> packed bf16 -> LDS
        #pragma unroll
        for (int r = 0; r < 6; r++) {
            int m = r * 256 + tid;                   // over 64 edges x 24 float4s
            int eL = m / 24, q = m - eL * 24;
            const float4 a = *(const float4*)&xf[ss[eL] * 96 + q * 4];
            const float4 b = *(const float4*)&xf[sd[eL] * 96 + q * 4];
            *(uint2*)&h2s[eL * WST + q * 4] =
                make_uint2(f2bf2(a.x * b.x, a.y * b.y), f2bf2(a.z * b.z, a.w * b.w));
        }
        __syncthreads();

        // phase 2: MFMA (A[m=lcol][k] from h2s; B from frag-major W1f, conflict-free)
        frag_cd accA[6], accB[6];
        #pragma unroll
        for (int nt = 0; nt < 6; nt++) {
            accA[nt] = (frag_cd){0.f, 0.f, 0.f, 0.f};
            if (DUAL) accB[nt] = (frag_cd){0.f, 0.f, 0.f, 0.f};
        }
        const int mrow = m0 + lcol;
        #pragma unroll
        for (int kt = 0; kt < 3; kt++) {
            const int k0 = kt * 32 + quad * 8;
            frag_ab afrag = *(const frag_ab*)&h2s[mrow * WST + k0];
            #pragma unroll
            for (int nt = 0; nt < 6; nt++) {
                const int f = ((nt * 3 + kt) * 4 + quad) * 16 + lcol;
                frag_ab bfragA = *(const frag_ab*)&W1f[f * 8];
                accA[nt] = __builtin_amdgcn_mfma_f32_16x16x32_bf16(afrag, bfragA, accA[nt], 0, 0, 0);
                if (DUAL) {
                    frag_ab bfragB = *(const frag_ab*)&W1f[9216 + f * 8];
                    accB[nt] = __builtin_amdgcn_mfma_f32_16x16x32_bf16(afrag, bfragB, accB[nt], 0, 0, 0);
                }
            }
        }
        // phase 3: +b1, prelu, dot W2, quad-reduce, tanh.  C/D: col=lcol, row=quad*4+reg.
        float psA[4] = {0.f, 0.f, 0.f, 0.f};
        float psB[4] = {0.f, 0.f, 0.f, 0.f};
        #pragma unroll
        for (int nt = 0; nt < 6; nt++) {
            float w2A = W2s[nt * 16 + lcol];
            float b1A = b1s[nt * 16 + lcol];
            #pragma unroll
            for (int reg = 0; reg < 4; reg++) {
                float u = accA[nt][reg] + b1A;
                u = u >= 0.f ? u : alphaA * u;
                psA[reg] += u * w2A;
            }
            if (DUAL) {
                float w2B = W2s[96 + nt * 16 + lcol];
                float b1B = b1s[96 + nt * 16 + lcol];
                #pragma unroll
                for (int reg = 0; reg < 4; reg++) {
                    float u = accB[nt][reg] + b1B;
                    u = u >= 0.f ? u : alphaB * u;
                    psB[reg] += u * w2B;
                }
            }
        }
        #pragma unroll
        for (int off = 1; off < 16; off <<= 1) {
            #pragma unroll
            for (int reg = 0; reg < 4; reg++) {
                psA[reg] += __shfl_xor(psA[reg], off, 64);
                if (DUAL) psB[reg] += __shfl_xor(psB[reg], off, 64);
            }
        }
        if (lcol == 0) {
            #pragma unroll
            for (int reg = 0; reg < 4; reg++) {
                int er = base + m0 + quad * 4 + reg;
                outA[er] = tanhf(psA[reg] + b2A);
                if (DUAL) outB[er] = tanhf(psB[reg] + b2B);
            }
        }
        __syncthreads();
    }
}

// ---------------- CSR build: count / scan / scatter ----------------
__global__ __launch_bounds__(256) void count_kernel(
    const int* __restrict__ dst, int* __restrict__ cnt)
{
    int e = blockIdx.x * 256 + threadIdx.x;          // over E, exact
    atomicAdd(&cnt[dst[e]], 1);
}

// single block, 1024 threads; 25600 = 1024 * 25
__global__ __launch_bounds__(1024) void scan_kernel(
    const int* __restrict__ cnt, int* __restrict__ off, int* __restrict__ cur)
{
    __shared__ int part[1024];
    const int tid = threadIdx.x;
    const int base = tid * 25;
    int loc[25];
    int s = 0;
    #pragma unroll
    for (int i = 0; i < 25; i++) { loc[i] = s; s += cnt[base + i]; }
    part[tid] = s;
    __syncthreads();
    for (int d = 1; d < 1024; d <<= 1) {
        int t = (tid >= d) ? part[tid - d] : 0;
        __syncthreads();
        part[tid] += t;
        __syncthreads();
    }
    const int basesum = part[tid] - s;
    #pragma unroll
    for (int i = 0; i < 25; i++) {
        int o = basesum + loc[i];
        off[base + i] = o;
        cur[base + i] = o;
    }
    if (tid == 1023) off[N_NODES] = part[1023];
}

__global__ __launch_bounds__(256) void scatter_kernel(
    const int* __restrict__ dst, int* __restrict__ cur, int* __restrict__ perm)
{
    int e = blockIdx.x * 256 + threadIdx.x;          // over E, exact
    int p = atomicAdd(&cur[dst[e]], 1);
    perm[p] = e;
}

// ---------------- fused: z = segsum(x[src]*e, dst) ; x_next = prelu(BN(LN(z + xin))) ----------------
__global__ __launch_bounds__(128) void agg_norm_kernel(
    const float* __restrict__ xf, const int* __restrict__ srcg,
    const float* __restrict__ ef,
    const int* __restrict__ off, const int* __restrict__ perm,
    const float* __restrict__ xin,
    const float* __restrict__ lng, const float* __restrict__ lnb,
    const float* __restrict__ bng, const float* __restrict__ bnb,
    const float* __restrict__ bnrm, const float* __restrict__ bnrv,
    const float* __restrict__ acta, int layer,
    float* __restrict__ xout)
{
    __shared__ float red[128];
    const int n = blockIdx.x;
    const int tid = threadIdx.x;
    const int beg = off[n], end = off[n + 1];
    float v = 0.f;
    if (tid < 96) {
        // unroll x4: 4 independent perm->src->row load chains in flight
        float v0 = 0.f, v1 = 0.f, v2 = 0.f, v3 = 0.f;
        int j = beg;
        for (; j + 4 <= end; j += 4) {
            const int e0 = perm[j],     e1 = perm[j + 1];
            const int e2 = perm[j + 2], e3 = perm[j + 3];
            v0 += xf[srcg[e0] * 96 + tid] * ef[e0];
            v1 += xf[srcg[e1] * 96 + tid] * ef[e1];
            v2 += xf[srcg[e2] * 96 + tid] * ef[e2];
            v3 += xf[srcg[e3] * 96 + tid] * ef[e3];
        }
        for (; j < end; j++) {
            const int e = perm[j];
            v0 += xf[srcg[e] * 96 + tid] * ef[e];
        }
        v = ((v0 + v1) + (v2 + v3)) + xin[n * 96 + tid];
    }
    red[tid] = (tid < 96) ? v : 0.f;
    __syncthreads();
    for (int sft = 64; sft > 0; sft >>= 1) {
        if (tid < sft) red[tid] += red[tid + sft];
        __syncthreads();
    }
    const float mean = red[0] * (1.f / 96.f);
    __syncthreads();
    const float d = (tid < 96) ? (v - mean) : 0.f;
    red[tid] = d * d;
    __syncthreads();
    for (int sft = 64; sft > 0; sft >>= 1) {
        if (tid < sft) red[tid] += red[tid + sft];
        __syncthreads();
    }
    const float rstd = rsqrtf(red[0] * (1.f / 96.f) + EPSV);
    if (tid < 96) {
        const int c = layer * 96 + tid;
        float y = d * rstd * lng[c] + lnb[c];
        y = (y - bnrm[c]) * rsqrtf(bnrv[c] + EPSV) * bng[c] + bnb[c];
        const float a = acta[layer];
        xout[n * 96 + tid] = y >= 0.f ? y : a * y;
    }
}

// ---------------- final: out[64-node tile] = hcat @ t2_w + t2_b  (MFMA, K=288 in 3x96) ----------------
__global__ __launch_bounds__(256) void final_mfma(
    const float* __restrict__ x0, const float* __restrict__ x1, const float* __restrict__ x2,
    const float* __restrict__ t2w, const float* __restrict__ t2b,
    float* __restrict__ out)
{
    __shared__ alignas(16) unsigned short As[64 * WST];
    __shared__ alignas(16) unsigned short Bs[128 * WST];

    const int tid  = threadIdx.x;
    const int lane = tid & 63;
    const int wv   = tid >> 6;
    const int quad = lane >> 4;
    const int lcol = lane & 15;
    const int node0 = blockIdx.x * 64;

    frag_cd acc[8];
    #pragma unroll
    for (int nt = 0; nt < 8; nt++) acc[nt] = (frag_cd){0.f, 0.f, 0.f, 0.f};

    for (int ck = 0; ck < 3; ck++) {
        const float* xc = (ck == 0) ? x0 : (ck == 1 ? x1 : x2);
        __syncthreads();
        #pragma unroll
        for (int r = 0; r < 6; r++) {
            int m = r * 256 + tid;
            int mm = m / 24, q = m - mm * 24;
            const float4 a = *(const float4*)&xc[(node0 + mm) * 96 + q * 4];
            *(uint2*)&As[mm * WST + q * 4] = make_uint2(f2bf2(a.x, a.y), f2bf2(a.z, a.w));
        }
        #pragma unroll
        for (int r = 0; r < 48; r++) {
            int idx = r * 256 + tid;
            int cc = idx >> 7, o = idx & 127;
            Bs[o * WST + cc] = f2bf(t2w[(ck * 96 + cc) * 128 + o]);
        }
        __syncthreads();
        const int mrow = wv * 16 + lcol;
        #pragma unroll
        for (int kt = 0; kt < 3; kt++) {
            const int k0 = kt * 32 + quad * 8;
            frag_ab afrag = *(const frag_ab*)&As[mrow * WST + k0];
            #pragma unroll
            for (int nt = 0; nt < 8; nt++) {
                frag_ab bfrag = *(const frag_ab*)&Bs[(nt * 16 + lcol) * WST + k0];
                acc[nt] = __builtin_amdgcn_mfma_f32_16x16x32_bf16(afrag, bfrag, acc[nt], 0, 0, 0);
            }
        }
    }
    const int node = node0 + wv * 16 + quad * 4;
    #pragma unroll
    for (int nt = 0; nt < 8; nt++) {
        const int o = nt * 16 + lcol;
        const float bias = t2b[o];
        #pragma unroll
        for (int reg = 0; reg < 4; reg++)
            out[(node + reg) * 128 + o] = acc[nt][reg] + bias;
    }
}

extern "C" void kernel_launch(void* const* d_in, const int* in_sizes, int n_in,
                              void* d_out, int out_size, void* d_ws, size_t ws_size,
                              hipStream_t stream)
{
    const float* h    = (const float*)d_in[0];
    const int*   src  = (const int*)d_in[1];
    const int*   dst  = (const int*)d_in[2];
    const float* tpw1 = (const float*)d_in[3];
    const float* tpb1 = (const float*)d_in[4];
    const float* tpa  = (const float*)d_in[5];
    const float* tpw2 = (const float*)d_in[6];
    const float* tpb2 = (const float*)d_in[7];
    const float* tmw1 = (const float*)d_in[8];
    const float* tmb1 = (const float*)d_in[9];
    const float* tma  = (const float*)d_in[10];
    const float* tmw2 = (const float*)d_in[11];
    const float* tmb2 = (const float*)d_in[12];
    const float* lng  = (const float*)d_in[13];
    const float* lnb  = (const float*)d_in[14];
    const float* bng  = (const float*)d_in[15];
    const float* bnb  = (const float*)d_in[16];
    const float* bnrm = (const float*)d_in[17];
    const float* bnrv = (const float*)d_in[18];
    const float* acta = (const float*)d_in[19];
    const float* gW1  = (const float*)d_in[20];
    const float* gb1  = (const float*)d_in[21];
    const float* ga   = (const float*)d_in[22];
    const float* gW2  = (const float*)d_in[23];
    const float* gb2  = (const float*)d_in[24];
    const float* t2w  = (const float*)d_in[25];
    const float* t2b  = (const float*)d_in[26];

    float* ws = (float*)d_ws;
    float* x0 = ws;                         // N*96
    float* x1 = x0 + N_NODES * 96;          // N*96
    float* x2 = x1 + N_NODES * 96;          // N*96
    float* eb = x2 + N_NODES * 96;          // E
    int* cnt  = (int*)(eb + N_EDGES);       // N
    int* off  = cnt + N_NODES;              // N+1
    int* cur  = off + N_NODES + 1;          // N
    int* perm = cur + N_NODES;              // E

    float* out = (float*)d_out;             // N*128 fp32
    float* ee  = out + N_NODES * 128;       // 2E fp32

    // ---- CSR build (dst-only; used by agg_norm) ----
    hipMemsetAsync(cnt, 0, N_NODES * sizeof(int), stream);
    count_kernel<<<N_EDGES / 256, 256, 0, stream>>>(dst, cnt);
    scan_kernel<<<1, 1024, 0, stream>>>(cnt, off, cur);
    scatter_kernel<<<N_EDGES / 256, 256, 0, stream>>>(dst, cur, perm);

    // ---- fused transform (t1+t2) ----
    transform_mfma<<<dim3(200, 2), 256, 0, stream>>>(
        h, tpw1, tpb1, tpa, tpw2, tpb2, tmw1, tmb1, tma, tmw2, tmb2, x0);

    // ---- layer 0 ----
    gate_kernel<false><<<1600, 256, 0, stream>>>(x0, src, dst, gW1, gb1, ga, gW2, gb2, 0, 0, eb, nullptr);
    agg_norm_kernel<<<N_NODES, 128, 0, stream>>>(x0, src, eb, off, perm, x0,
        lng, lnb, bng, bnb, bnrm, bnrv, acta, 0, x1);

    // ---- fused: es[layer0](x1) -> ee   AND   agg-gate[layer1](x1) -> eb ----
    gate_kernel<true><<<1600, 256, 0, stream>>>(x1, src, dst, gW1, gb1, ga, gW2, gb2, 0, 1, ee, eb);

    // ---- layer 1 ----
    agg_norm_kernel<<<N_NODES, 128, 0, stream>>>(x1, src, eb, off, perm, x1,
        lng, lnb, bng, bnb, bnrm, bnrv, acta, 1, x2);
    gate_kernel<false><<<1600, 256, 0, stream>>>(x2, src, dst, gW1, gb1, ga, gW2, gb2, 1, 0, ee + N_EDGES, nullptr);

    // ---- readout ----
    final_mfma<<<N_NODES / 64, 256, 0, stream>>>(x0, x1, x2, t2w, t2b, out);
}

// Round 14
// 496.055 us; speedup vs baseline: 1.3064x; 1.0141x over previous
//
#include <hip/hip_runtime.h>

#define N_NODES 25600
#define N_EDGES 409600
#define EPSV 1e-5f

__device__ __forceinline__ unsigned short f2bf(float f) {
    unsigned int x = __float_as_uint(f);
    x += 0x7fffu + ((x >> 16) & 1u);
    return (unsigned short)(x >> 16);
}
// packed 2x f32 -> bf16x2 in one instruction where available (gfx950: v_cvt_pk_bf16_f32)
__device__ __forceinline__ unsigned int f2bf2(float a, float b) {
#if __has_builtin(__builtin_amdgcn_cvt_pk_bf16_f32)
    auto r = __builtin_amdgcn_cvt_pk_bf16_f32(a, b);
    unsigned int u;
    __builtin_memcpy(&u, &r, 4);
    return u;
#else
    return (unsigned int)f2bf(a) | ((unsigned int)f2bf(b) << 16);
#endif
}
// product of two bf16x2 pairs -> bf16x2
__device__ __forceinline__ unsigned int bfmul2(unsigned int a, unsigned int b) {
    float alo = __uint_as_float(a << 16), ahi = __uint_as_float(a & 0xffff0000u);
    float blo = __uint_as_float(b << 16), bhi = __uint_as_float(b & 0xffff0000u);
    return f2bf2(alo * blo, ahi * bhi);
}

using frag_ab = __attribute__((ext_vector_type(8))) short;  // 8 bf16 = 4 VGPRs
using frag_cd = __attribute__((ext_vector_type(4))) float;

#define WST 104   // h2s/final LDS row stride (bf16): 208 B, 16B-aligned; A-read aliasing 2-way = free
#define TWST 72   // transform weight LDS stride (bf16)
#define THST 200  // transform h/y1 LDS stride (bf16)

// ---------------- fused transform: x[n,0:96] = W2g·prelu(W1g·h[n]+b1)+b2, grouped, MFMA ----------------
// Also emits the bf16 mirror xb (gathered by the gate).
__global__ __launch_bounds__(256) void transform_mfma(
    const float* __restrict__ h,
    const float* __restrict__ tpw1, const float* __restrict__ tpb1, const float* __restrict__ tpa,
    const float* __restrict__ tpw2, const float* __restrict__ tpb2,
    const float* __restrict__ tmw1, const float* __restrict__ tmb1, const float* __restrict__ tma,
    const float* __restrict__ tmw2, const float* __restrict__ tmb2,
    float* __restrict__ xout, unsigned short* __restrict__ xb)
{
    __shared__ alignas(16) unsigned short W1s[192 * TWST]; // [o][i] bf16
    __shared__ alignas(16) unsigned short W2s[96 * TWST];  // [o][i] bf16
    __shared__ alignas(16) unsigned short hs[64 * THST];   // [m][c] bf16; y1 overwrites in place
    __shared__ float b1s[192];
    __shared__ float b2s[96];

    const int tid = threadIdx.x;
    const int s = blockIdx.y;
    const float* w1 = s ? tmw1 : tpw1;
    const float* b1 = s ? tmb1 : tpb1;
    const float* w2 = s ? tmw2 : tpw2;
    const float* b2 = s ? tmb2 : tpb2;
    const float alpha = (s ? tma : tpa)[0];

    #pragma unroll
    for (int r = 0; r < 12; r++) {
        int idx4 = r * 256 + tid;                    // over 192*16
        int o = idx4 >> 4, i4 = (idx4 & 15) * 4;
        const float4 a = *(const float4*)&w1[o * 64 + i4];
        *(uint2*)&W1s[o * TWST + i4] = make_uint2(f2bf2(a.x, a.y), f2bf2(a.z, a.w));
    }
    #pragma unroll
    for (int r = 0; r < 6; r++) {
        int idx4 = r * 256 + tid;                    // over 96*16
        int o = idx4 >> 4, i4 = (idx4 & 15) * 4;
        const float4 a = *(const float4*)&w2[o * 64 + i4];
        *(uint2*)&W2s[o * TWST + i4] = make_uint2(f2bf2(a.x, a.y), f2bf2(a.z, a.w));
    }
    if (tid < 192) b1s[tid] = b1[tid];
    if (tid < 96) b2s[tid] = b2[tid];
    __syncthreads();

    const int lane = tid & 63;
    const int wv = tid >> 6;
    const int quad = lane >> 4;
    const int lcol = lane & 15;
    const int m0 = wv * 16;
    const int j0 = blockIdx.x * 64;

    #pragma unroll
    for (int r = 0; r < 12; r++) {
        int idx = r * 256 + tid;                     // over 64*48 float4s
        int m = idx / 48, q = idx - m * 48;
        const float4 a = *(const float4*)&h[(2 * (j0 + m) + s) * 192 + q * 4];
        *(uint2*)&hs[m * THST + q * 4] = make_uint2(f2bf2(a.x, a.y), f2bf2(a.z, a.w));
    }
    __syncthreads();

    const int arow = (m0 + lcol) * THST;
    #pragma unroll
    for (int g = 0; g < 3; g++) {
        frag_cd acc[4];
        #pragma unroll
        for (int nt = 0; nt < 4; nt++) acc[nt] = (frag_cd){0.f, 0.f, 0.f, 0.f};
        #pragma unroll
        for (int kt = 0; kt < 2; kt++) {
            const int k0 = kt * 32 + quad * 8;
            frag_ab af = *(const frag_ab*)&hs[arow + g * 64 + k0];
            #pragma unroll
            for (int nt = 0; nt < 4; nt++) {
                frag_ab bf = *(const frag_ab*)&W1s[(g * 64 + nt * 16 + lcol) * TWST + k0];
                acc[nt] = __builtin_amdgcn_mfma_f32_16x16x32_bf16(af, bf, acc[nt], 0, 0, 0);
            }
        }
        #pragma unroll
        for (int nt = 0; nt < 4; nt++) {
            const int o = g * 64 + nt * 16 + lcol;
            const float bv = b1s[o];
            #pragma unroll
            for (int reg = 0; reg < 4; reg++) {
                float u = acc[nt][reg] + bv;
                u = u >= 0.f ? u : alpha * u;
                hs[(m0 + quad * 4 + reg) * THST + o] = f2bf(u);
            }
        }
    }
    #pragma unroll
    for (int g2 = 0; g2 < 3; g2++) {
        frag_cd acc[2];
        acc[0] = (frag_cd){0.f, 0.f, 0.f, 0.f};
        acc[1] = (frag_cd){0.f, 0.f, 0.f, 0.f};
        #pragma unroll
        for (int kt = 0; kt < 2; kt++) {
            const int k0 = kt * 32 + quad * 8;
            frag_ab af = *(const frag_ab*)&hs[arow + g2 * 64 + k0];
            #pragma unroll
            for (int nt = 0; nt < 2; nt++) {
                frag_ab bf = *(const frag_ab*)&W2s[(g2 * 32 + nt * 16 + lcol) * TWST + k0];
                acc[nt] = __builtin_amdgcn_mfma_f32_16x16x32_bf16(af, bf, acc[nt], 0, 0, 0);
            }
        }
        #pragma unroll
        for (int nt = 0; nt < 2; nt++) {
            const int o2 = g2 * 32 + nt * 16 + lcol;
            const float bv = b2s[o2];
            #pragma unroll
            for (int reg = 0; reg < 4; reg++) {
                const int node = 2 * (j0 + m0 + quad * 4 + reg) + s;
                const float v = acc[nt][reg] + bv;
                xout[node * 96 + o2] = v;
                xb[node * 96 + o2] = f2bf(v);
            }
        }
    }
}

// ---------------- gate (MFMA): e = tanh(prelu((x[dst]*x[src]) @ W1 + b1) @ W2 + b2) ----------------
// R13 structure (frag-major W1, 4-tile prologue index staging) + BF16 GATHER: reads the
// 4.9 MB bf16 mirror xb (half the traffic of fp32; nearly L2-resident per XCD).
template<bool DUAL>
__global__ __launch_bounds__(256) void gate_kernel(
    const unsigned short* __restrict__ xb,
    const int* __restrict__ src, const int* __restrict__ dst,
    const float* __restrict__ gW1, const float* __restrict__ gb1,
    const float* __restrict__ ga,  const float* __restrict__ gW2,
    const float* __restrict__ gb2, int layerA, int layerB,
    float* __restrict__ outA, float* __restrict__ outB)
{
    // frag-major: entry f = ((nt*3+kt)*4+quad)*16+lcol holds B[n=nt*16+lcol][k=kt*32+quad*8 ..+8]
    __shared__ alignas(16) unsigned short W1f[(DUAL ? 2 : 1) * 9216];
    __shared__ alignas(16) unsigned short h2s[64 * WST];    // [edge][k] bf16
    __shared__ float W2s[(DUAL ? 2 : 1) * 96];
    __shared__ float b1s[(DUAL ? 2 : 1) * 96];
    __shared__ int ssrc4[256];
    __shared__ int sdst4[256];

    const int tid = threadIdx.x;
    {
        // coalesced global read, frag-major LDS write (one-time)
        const float* W1p = gW1 + layerA * 9216;
        const float* W1q = gW1 + layerB * 9216;
        for (int idx = tid; idx < 9216; idx += 256) {
            int k = idx / 96, n = idx - k * 96;
            int kt = k >> 5, quad = (k & 31) >> 3, j = k & 7;
            int nt = n >> 4, lc = n & 15;
            int f = ((nt * 3 + kt) * 4 + quad) * 16 + lc;
            W1f[f * 8 + j] = f2bf(W1p[idx]);
            if (DUAL) W1f[9216 + f * 8 + j] = f2bf(W1q[idx]);
        }
        // stage all 4 tiles' edge indices: thread i -> tile i>>6, slot i&63
        int e = (blockIdx.x + (tid >> 6) * 1600) * 64 + (tid & 63);
        ssrc4[tid] = src[e];
        sdst4[tid] = dst[e];
    }
    if (tid < 96) {
        W2s[tid] = gW2[layerA * 96 + tid];
        b1s[tid] = gb1[layerA * 96 + tid];
        if (DUAL) {
            W2s[96 + tid] = gW2[layerB * 96 + tid];
            b1s[96 + tid] = gb1[layerB * 96 + tid];
        }
    }
    const float alphaA = ga[layerA];
    const float b2A = gb2[layerA];
    const float alphaB = DUAL ? ga[layerB] : 0.f;
    const float b2B = DUAL ? gb2[layerB] : 0.f;
    __syncthreads();

    const int lane = tid & 63;
    const int wv   = tid >> 6;
    const int quad = lane >> 4;
    const int lcol = lane & 15;
    const int m0   = wv * 16;

    #pragma unroll 1
    for (int t = 0; t < 4; t++) {
        const int base = (blockIdx.x + t * 1600) * 64;
        const int* ss = &ssrc4[t * 64];
        const int* sd = &sdst4[t * 64];
        // phase 1: h2 = xb[src]*xb[dst], bf16 uint4 row gather (16B = 8 elems) -> LDS
        #pragma unroll
        for (int r = 0; r < 3; r++) {
            int m = r * 256 + tid;                   // 0..767 over 64 edges x 12 ushort8
            int eL = m / 12, q = m - eL * 12;
            const uint4 a = *(const uint4*)&xb[ss[eL] * 96 + q * 8];
            const uint4 b = *(const uint4*)&xb[sd[eL] * 96 + q * 8];
            uint4 p;
            p.x = bfmul2(a.x, b.x);
            p.y = bfmul2(a.y, b.y);
            p.z = bfmul2(a.z, b.z);
            p.w = bfmul2(a.w, b.w);
            *(uint4*)&h2s[eL * WST + q * 8] = p;
        }
        __syncthreads();

        // phase 2: MFMA (A[m=lcol][k] from h2s; B from frag-major W1f, conflict-free)
        frag_cd accA[6], accB[6];
        #pragma unroll
        for (int nt = 0; nt < 6; nt++) {
            accA[nt] = (frag_cd){0.f, 0.f, 0.f, 0.f};
            if (DUAL) accB[nt] = (frag_cd){0.f, 0.f, 0.f, 0.f};
        }
        const int mrow = m0 + lcol;
        #pragma unroll
        for (int kt = 0; kt < 3; kt++) {
            const int k0 = kt * 32 + quad * 8;
            frag_ab afrag = *(const frag_ab*)&h2s[mrow * WST + k0];
            #pragma unroll
            for (int nt = 0; nt < 6; nt++) {
                const int f = ((nt * 3 + kt) * 4 + quad) * 16 + lcol;
                frag_ab bfragA = *(const frag_ab*)&W1f[f * 8];
                accA[nt] = __builtin_amdgcn_mfma_f32_16x16x32_bf16(afrag, bfragA, accA[nt], 0, 0, 0);
                if (DUAL) {
                    frag_ab bfragB = *(const frag_ab*)&W1f[9216 + f * 8];
                    accB[nt] = __builtin_amdgcn_mfma_f32_16x16x32_bf16(afrag, bfragB, accB[nt], 0, 0, 0);
                }
            }
        }
        // phase 3: +b1, prelu, dot W2, quad-reduce, tanh.  C/D: col=lcol, row=quad*4+reg.
        float psA[4] = {0.f, 0.f, 0.f, 0.f};
        float psB[4] = {0.f, 0.f, 0.f, 0.f};
        #pragma unroll
        for (int nt = 0; nt < 6; nt++) {
            float w2A = W2s[nt * 16 + lcol];
            float b1A = b1s[nt * 16 + lcol];
            #pragma unroll
            for (int reg = 0; reg < 4; reg++) {
                float u = accA[nt][reg] + b1A;
                u = u >= 0.f ? u : alphaA * u;
                psA[reg] += u * w2A;
            }
            if (DUAL) {
                float w2B = W2s[96 + nt * 16 + lcol];
                float b1B = b1s[96 + nt * 16 + lcol];
                #pragma unroll
                for (int reg = 0; reg < 4; reg++) {
                    float u = accB[nt][reg] + b1B;
                    u = u >= 0.f ? u : alphaB * u;
                    psB[reg] += u * w2B;
                }
            }
        }
        #pragma unroll
        for (int off = 1; off < 16; off <<= 1) {
            #pragma unroll
            for (int reg = 0; reg < 4; reg++) {
                psA[reg] += __shfl_xor(psA[reg], off, 64);
                if (DUAL) psB[reg] += __shfl_xor(psB[reg], off, 64);
            }
        }
        if (lcol == 0) {
            #pragma unroll
            for (int reg = 0; reg < 4; reg++) {
                int er = base + m0 + quad * 4 + reg;
                outA[er] = tanhf(psA[reg] + b2A);
                if (DUAL) outB[er] = tanhf(psB[reg] + b2B);
            }
        }
        __syncthreads();
    }
}

// ---------------- CSR build: count / scan / scatter ----------------
__global__ __launch_bounds__(256) void count_kernel(
    const int* __restrict__ dst, int* __restrict__ cnt)
{
    int e = blockIdx.x * 256 + threadIdx.x;          // over E, exact
    atomicAdd(&cnt[dst[e]], 1);
}

// single block, 1024 threads; 25600 = 1024 * 25
__global__ __launch_bounds__(1024) void scan_kernel(
    const int* __restrict__ cnt, int* __restrict__ off, int* __restrict__ cur)
{
    __shared__ int part[1024];
    const int tid = threadIdx.x;
    const int base = tid * 25;
    int loc[25];
    int s = 0;
    #pragma unroll
    for (int i = 0; i < 25; i++) { loc[i] = s; s += cnt[base + i]; }
    part[tid] = s;
    __syncthreads();
    for (int d = 1; d < 1024; d <<= 1) {
        int t = (tid >= d) ? part[tid - d] : 0;
        __syncthreads();
        part[tid] += t;
        __syncthreads();
    }
    const int basesum = part[tid] - s;
    #pragma unroll
    for (int i = 0; i < 25; i++) {
        int o = basesum + loc[i];
        off[base + i] = o;
        cur[base + i] = o;
    }
    if (tid == 1023) off[N_NODES] = part[1023];
}

__global__ __launch_bounds__(256) void scatter_kernel(
    const int* __restrict__ dst, int* __restrict__ cur, int* __restrict__ perm)
{
    int e = blockIdx.x * 256 + threadIdx.x;          // over E, exact
    int p = atomicAdd(&cur[dst[e]], 1);
    perm[p] = e;
}

// ---------------- fused: z = segsum(x[src]*e, dst) ; x_next = prelu(BN(LN(z + xin))) ----------------
// Also emits the bf16 mirror xb of x_next (single reused buffer, gate-only consumer).
__global__ __launch_bounds__(128) void agg_norm_kernel(
    const float* __restrict__ xf, const int* __restrict__ srcg,
    const float* __restrict__ ef,
    const int* __restrict__ off, const int* __restrict__ perm,
    const float* __restrict__ xin,
    const float* __restrict__ lng, const float* __restrict__ lnb,
    const float* __restrict__ bng, const float* __restrict__ bnb,
    const float* __restrict__ bnrm, const float* __restrict__ bnrv,
    const float* __restrict__ acta, int layer,
    float* __restrict__ xout, unsigned short* __restrict__ xb)
{
    __shared__ float red[128];
    const int n = blockIdx.x;
    const int tid = threadIdx.x;
    const int beg = off[n], end = off[n + 1];
    float v = 0.f;
    if (tid < 96) {
        // unroll x4: 4 independent perm->src->row load chains in flight
        float v0 = 0.f, v1 = 0.f, v2 = 0.f, v3 = 0.f;
        int j = beg;
        for (; j + 4 <= end; j += 4) {
            const int e0 = perm[j],     e1 = perm[j + 1];
            const int e2 = perm[j + 2], e3 = perm[j + 3];
            v0 += xf[srcg[e0] * 96 + tid] * ef[e0];
            v1 += xf[srcg[e1] * 96 + tid] * ef[e1];
            v2 += xf[srcg[e2] * 96 + tid] * ef[e2];
            v3 += xf[srcg[e3] * 96 + tid] * ef[e3];
        }
        for (; j < end; j++) {
            const int e = perm[j];
            v0 += xf[srcg[e] * 96 + tid] * ef[e];
        }
        v = ((v0 + v1) + (v2 + v3)) + xin[n * 96 + tid];
    }
    red[tid] = (tid < 96) ? v : 0.f;
    __syncthreads();
    for (int sft = 64; sft > 0; sft >>= 1) {
        if (tid < sft) red[tid] += red[tid + sft];
        __syncthreads();
    }
    const float mean = red[0] * (1.f / 96.f);
    __syncthreads();
    const float d = (tid < 96) ? (v - mean) : 0.f;
    red[tid] = d * d;
    __syncthreads();
    for (int sft = 64; sft > 0; sft >>= 1) {
        if (tid < sft) red[tid] += red[tid + sft];
        __syncthreads();
    }
    const float rstd = rsqrtf(red[0] * (1.f / 96.f) + EPSV);
    if (tid < 96) {
        const int c = layer * 96 + tid;
        float y = d * rstd * lng[c] + lnb[c];
        y = (y - bnrm[c]) * rsqrtf(bnrv[c] + EPSV) * bng[c] + bnb[c];
        const float a = acta[layer];
        const float o = y >= 0.f ? y : a * y;
        xout[n * 96 + tid] = o;
        xb[n * 96 + tid] = f2bf(o);
    }
}

// ---------------- final: out[64-node tile] = hcat @ t2_w + t2_b  (MFMA, K=288 in 3x96) ----------------
__global__ __launch_bounds__(256) void final_mfma(
    const float* __restrict__ x0, const float* __restrict__ x1, const float* __restrict__ x2,
    const float* __restrict__ t2w, const float* __restrict__ t2b,
    float* __restrict__ out)
{
    __shared__ alignas(16) unsigned short As[64 * WST];
    __shared__ alignas(16) unsigned short Bs[128 * WST];

    const int tid  = threadIdx.x;
    const int lane = tid & 63;
    const int wv   = tid >> 6;
    const int quad = lane >> 4;
    const int lcol = lane & 15;
    const int node0 = blockIdx.x * 64;

    frag_cd acc[8];
    #pragma unroll
    for (int nt = 0; nt < 8; nt++) acc[nt] = (frag_cd){0.f, 0.f, 0.f, 0.f};

    for (int ck = 0; ck < 3; ck++) {
        const float* xc = (ck == 0) ? x0 : (ck == 1 ? x1 : x2);
        __syncthreads();
        #pragma unroll
        for (int r = 0; r < 6; r++) {
            int m = r * 256 + tid;
            int mm = m / 24, q = m - mm * 24;
            const float4 a = *(const float4*)&xc[(node0 + mm) * 96 + q * 4];
            *(uint2*)&As[mm * WST + q * 4] = make_uint2(f2bf2(a.x, a.y), f2bf2(a.z, a.w));
        }
        #pragma unroll
        for (int r = 0; r < 48; r++) {
            int idx = r * 256 + tid;
            int cc = idx >> 7, o = idx & 127;
            Bs[o * WST + cc] = f2bf(t2w[(ck * 96 + cc) * 128 + o]);
        }
        __syncthreads();
        const int mrow = wv * 16 + lcol;
        #pragma unroll
        for (int kt = 0; kt < 3; kt++) {
            const int k0 = kt * 32 + quad * 8;
            frag_ab afrag = *(const frag_ab*)&As[mrow * WST + k0];
            #pragma unroll
            for (int nt = 0; nt < 8; nt++) {
                frag_ab bfrag = *(const frag_ab*)&Bs[(nt * 16 + lcol) * WST + k0];
                acc[nt] = __builtin_amdgcn_mfma_f32_16x16x32_bf16(afrag, bfrag, acc[nt], 0, 0, 0);
            }
        }
    }
    const int node = node0 + wv * 16 + quad * 4;
    #pragma unroll
    for (int nt = 0; nt < 8; nt++) {
        const int o = nt * 16 + lcol;
        const float bias = t2b[o];
        #pragma unroll
        for (int reg = 0; reg < 4; reg++)
            out[(node + reg) * 128 + o] = acc[nt][reg] + bias;
    }
}

extern "C" void kernel_launch(void* const* d_in, const int* in_sizes, int n_in,
                              void* d_out, int out_size, void* d_ws, size_t ws_size,
                              hipStream_t stream)
{
    const float* h    = (const float*)d_in[0];
    const int*   src  = (const int*)d_in[1];
    const int*   dst  = (const int*)d_in[2];
    const float* tpw1 = (const float*)d_in[3];
    const float* tpb1 = (const float*)d_in[4];
    const float* tpa  = (const float*)d_in[5];
    const float* tpw2 = (const float*)d_in[6];
    const float* tpb2 = (const float*)d_in[7];
    const float* tmw1 = (const float*)d_in[8];
    const float* tmb1 = (const float*)d_in[9];
    const float* tma  = (const float*)d_in[10];
    const float* tmw2 = (const float*)d_in[11];
    const float* tmb2 = (const float*)d_in[12];
    const float* lng  = (const float*)d_in[13];
    const float* lnb  = (const float*)d_in[14];
    const float* bng  = (const float*)d_in[15];
    const float* bnb  = (const float*)d_in[16];
    const float* bnrm = (const float*)d_in[17];
    const float* bnrv = (const float*)d_in[18];
    const float* acta = (const float*)d_in[19];
    const float* gW1  = (const float*)d_in[20];
    const float* gb1  = (const float*)d_in[21];
    const float* ga   = (const float*)d_in[22];
    const float* gW2  = (const float*)d_in[23];
    const float* gb2  = (const float*)d_in[24];
    const float* t2w  = (const float*)d_in[25];
    const float* t2b  = (const float*)d_in[26];

    float* ws = (float*)d_ws;
    float* x0 = ws;                         // N*96 f32
    float* x1 = x0 + N_NODES * 96;          // N*96 f32
    float* x2 = x1 + N_NODES * 96;          // N*96 f32
    float* eb = x2 + N_NODES * 96;          // E f32
    int* cnt  = (int*)(eb + N_EDGES);       // N
    int* off  = cnt + N_NODES;              // N+1
    int* cur  = off + N_NODES + 1;          // N
    int* perm = cur + N_NODES;              // E
    unsigned short* xb = (unsigned short*)(perm + N_EDGES);  // N*96 bf16 (reused mirror)

    float* out = (float*)d_out;             // N*128 fp32
    float* ee  = out + N_NODES * 128;       // 2E fp32

    // ---- CSR build (dst-only; used by agg_norm) ----
    hipMemsetAsync(cnt, 0, N_NODES * sizeof(int), stream);
    count_kernel<<<N_EDGES / 256, 256, 0, stream>>>(dst, cnt);
    scan_kernel<<<1, 1024, 0, stream>>>(cnt, off, cur);
    scatter_kernel<<<N_EDGES / 256, 256, 0, stream>>>(dst, cur, perm);

    // ---- fused transform (t1+t2): x0 fp32 + xb = bf16(x0) ----
    transform_mfma<<<dim3(200, 2), 256, 0, stream>>>(
        h, tpw1, tpb1, tpa, tpw2, tpb2, tmw1, tmb1, tma, tmw2, tmb2, x0, xb);

    // ---- layer 0 ----
    gate_kernel<false><<<1600, 256, 0, stream>>>(xb, src, dst, gW1, gb1, ga, gW2, gb2, 0, 0, eb, nullptr);
    agg_norm_kernel<<<N_NODES, 128, 0, stream>>>(x0, src, eb, off, perm, x0,
        lng, lnb, bng, bnb, bnrm, bnrv, acta, 0, x1, xb);   // xb <- bf16(x1)

    // ---- fused: es[layer0](x1) -> ee   AND   agg-gate[layer1](x1) -> eb ----
    gate_kernel<true><<<1600, 256, 0, stream>>>(xb, src, dst, gW1, gb1, ga, gW2, gb2, 0, 1, ee, eb);

    // ---- layer 1 ----
    agg_norm_kernel<<<N_NODES, 128, 0, stream>>>(x1, src, eb, off, perm, x1,
        lng, lnb, bng, bnb, bnrm, bnrv, acta, 1, x2, xb);   // xb <- bf16(x2)
    gate_kernel<false><<<1600, 256, 0, stream>>>(xb, src, dst, gW1, gb1, ga, gW2, gb2, 1, 0, ee + N_EDGES, nullptr);

    // ---- readout ----
    final_mfma<<<N_NODES / 64, 256, 0, stream>>>(x0, x1, x2, t2w, t2b, out);
}